// Round 1
// baseline (51.352 us; speedup 1.0000x reference)
//
#include <hip/hip_runtime.h>

// ConcatAttention: B=4, SQ=SK=256, DQ=DK=DV=256, D=512
// score[b,q,k] = sum_h W2[h]*leaky(q_h+k_h+b1)
//   leaky(x) = 0.505x + 0.495|x|  ->  score = qlin[q] + klin[k] + sum_h c2[h]*|t|
//
// ws layout (floats):
//   hh   [2048][512] : rows 0..1023 = q_h (b*256+q), 1024..2047 = k_h + b1
//   lin  [2048]      : 0.505 * sum_h W2[h]*hh[row][h]
//   part [4][4][256][256] : partial |.| scores per h-block of 128
//   flag [1] (int)   : mask dtype: 1 = byte, 0 = int32

#define HH_OFF   0
#define LIN_OFF  (2048 * 512)
#define PART_OFF (LIN_OFF + 2048)
#define FLAG_OFF (PART_OFF + 4 * 4 * 256 * 256)

// ---------------- K1: fp32 GEMM  hh = [Q;K] @ W1half^T (+b1 for K rows) ----
__global__ __launch_bounds__(256) void k1_gemm(const float* __restrict__ Q,
                                               const float* __restrict__ Kin,
                                               const float* __restrict__ W1,
                                               const float* __restrict__ b1,
                                               float* __restrict__ hh) {
  const int bm = blockIdx.x & 31;   // 32 row blocks of 64 (M = 2048)
  const int bn = blockIdx.x >> 5;   // 8  col blocks of 64 (N = 512)
  const int m0 = bm * 64, n0 = bn * 64;
  const bool isK = (m0 >= 1024);
  const float* A = isK ? (Kin + (m0 - 1024) * 256) : (Q + m0 * 256);
  const int off = isK ? 256 : 0;
  __shared__ float As[32][68];  // [k][m], stride 68 keeps 16B align, spreads banks
  __shared__ float Bs[32][68];  // [k][n]
  const int t = threadIdx.x;
  const int tx = t & 15, ty = t >> 4;
  float acc[4][4] = {};
  for (int k0 = 0; k0 < 256; k0 += 32) {
#pragma unroll
    for (int s = 0; s < 2; ++s) {
      int id = t + s * 256;
      int row = id >> 3, c4 = (id & 7) * 4;
      float4 a = *(const float4*)&A[row * 256 + k0 + c4];
      As[c4 + 0][row] = a.x; As[c4 + 1][row] = a.y;
      As[c4 + 2][row] = a.z; As[c4 + 3][row] = a.w;
      float4 b = *(const float4*)&W1[(n0 + row) * 512 + off + k0 + c4];
      Bs[c4 + 0][row] = b.x; Bs[c4 + 1][row] = b.y;
      Bs[c4 + 2][row] = b.z; Bs[c4 + 3][row] = b.w;
    }
    __syncthreads();
#pragma unroll
    for (int kk = 0; kk < 32; ++kk) {
      float4 a4 = *(const float4*)&As[kk][ty * 4];
      float4 b4 = *(const float4*)&Bs[kk][tx * 4];
      float av[4] = {a4.x, a4.y, a4.z, a4.w};
      float bv[4] = {b4.x, b4.y, b4.z, b4.w};
#pragma unroll
      for (int ii = 0; ii < 4; ++ii)
#pragma unroll
        for (int jj = 0; jj < 4; ++jj)
          acc[ii][jj] = fmaf(av[ii], bv[jj], acc[ii][jj]);
    }
    __syncthreads();
  }
  const int h = n0 + tx * 4;
  float4 bias = make_float4(0.f, 0.f, 0.f, 0.f);
  if (isK) bias = *(const float4*)&b1[h];
#pragma unroll
  for (int ii = 0; ii < 4; ++ii) {
    int row = m0 + ty * 4 + ii;
    float4 o;
    o.x = acc[ii][0] + bias.x;
    o.y = acc[ii][1] + bias.y;
    o.z = acc[ii][2] + bias.z;
    o.w = acc[ii][3] + bias.w;
    *(float4*)&hh[row * 512 + h] = o;
  }
}

// ---------------- K1b: per-row linear term + mask dtype probe --------------
__global__ __launch_bounds__(256) void k1b_lin(const float* __restrict__ hh,
                                               const float* __restrict__ W2,
                                               const void* __restrict__ maskp,
                                               float* __restrict__ lin,
                                               int* __restrict__ flagp) {
  const int t = threadIdx.x;
  if (blockIdx.x == 0) {
    __shared__ int sflag;
    if (t == 0) sflag = 0;
    __syncthreads();
    const unsigned char* mb = (const unsigned char*)maskp;
    int nz = mb[t * 4 + 1] | mb[t * 4 + 2] | mb[t * 4 + 3];
    if (nz) atomicOr(&sflag, 1);
    __syncthreads();
    if (t == 0) *flagp = sflag;  // 1 => byte mask, 0 => int32 mask
  }
  const int w = t >> 6, lane = t & 63;
  const int row = blockIdx.x * 4 + w;
  const float* hr = hh + row * 512;
  float p = 0.f;
#pragma unroll
  for (int u = 0; u < 8; ++u) p = fmaf(W2[lane + 64 * u], hr[lane + 64 * u], p);
#pragma unroll
  for (int o = 32; o; o >>= 1) p += __shfl_xor(p, o, 64);
  if (lane == 0) lin[row] = 0.505f * p;
}

// ---------------- K2: abs-score partials ----------------------------------
// block: (b, qb:64 rows, kb:64 cols, hb: h-range 128); 4 waves split h by 32.
// wave tile 64x64, lane (i=lane&7 -> q rows i+8r, j=lane>>3 -> k rows j+8c)
__global__ __launch_bounds__(256) void k2_abs(const float* __restrict__ hh,
                                              const float* __restrict__ W2,
                                              float* __restrict__ part) {
  const int idx = blockIdx.x;
  const int hb = idx & 3, kb = (idx >> 2) & 3, qb = (idx >> 4) & 3, b = idx >> 6;
  __shared__ float smem[2 * 64 * 132 + 128];
  float* qs = smem;                  // [64][132]
  float* ks = smem + 64 * 132;       // [64][132]
  float* c2s = smem + 2 * 64 * 132;  // [128]
  const int t = threadIdx.x;
  const float* qbase = hh + (size_t)(b * 256 + qb * 64) * 512 + hb * 128;
  const float* kbase = hh + (size_t)(1024 + b * 256 + kb * 64) * 512 + hb * 128;
#pragma unroll
  for (int s = 0; s < 8; ++s) {
    int id = t + s * 256;
    int row = id >> 5, c4 = (id & 31) * 4;
    *(float4*)&qs[row * 132 + c4] = *(const float4*)&qbase[row * 512 + c4];
    *(float4*)&ks[row * 132 + c4] = *(const float4*)&kbase[row * 512 + c4];
  }
  if (t < 32) {
    float4 wv = *(const float4*)&W2[hb * 128 + t * 4];
    c2s[t * 4 + 0] = 0.495f * wv.x;
    c2s[t * 4 + 1] = 0.495f * wv.y;
    c2s[t * 4 + 2] = 0.495f * wv.z;
    c2s[t * 4 + 3] = 0.495f * wv.w;
  }
  __syncthreads();
  const int w = t >> 6, lane = t & 63;
  const int i = lane & 7, j = lane >> 3;
  const int h0 = w * 32;
  float acc[8][8] = {};
#pragma unroll 1
  for (int h4 = 0; h4 < 8; ++h4) {
    const int hc = h0 + h4 * 4;
    const float4 c2 = *(const float4*)&c2s[hc];
    float4 kf[8];
#pragma unroll
    for (int c = 0; c < 8; ++c) kf[c] = *(const float4*)&ks[(j + 8 * c) * 132 + hc];
#pragma unroll
    for (int r = 0; r < 8; ++r) {
      float4 qf = *(const float4*)&qs[(i + 8 * r) * 132 + hc];
#pragma unroll
      for (int c = 0; c < 8; ++c) {
        acc[r][c] = fmaf(c2.x, fabsf(qf.x + kf[c].x), acc[r][c]);
        acc[r][c] = fmaf(c2.y, fabsf(qf.y + kf[c].y), acc[r][c]);
        acc[r][c] = fmaf(c2.z, fabsf(qf.z + kf[c].z), acc[r][c]);
        acc[r][c] = fmaf(c2.w, fabsf(qf.w + kf[c].w), acc[r][c]);
      }
    }
  }
  __syncthreads();
  float* red = smem;  // [4][64][66] = 16896 floats, fits in qs+ks region
#pragma unroll
  for (int r = 0; r < 8; ++r)
#pragma unroll
    for (int c = 0; c < 8; ++c)
      red[(w * 64 + i + 8 * r) * 66 + (j + 8 * c)] = acc[r][c];
  __syncthreads();
  float* dst = part + (size_t)((hb * 4 + b) * 256 + qb * 64) * 256 + kb * 64;
#pragma unroll
  for (int s = 0; s < 16; ++s) {
    int id = t + s * 256;
    int row = id >> 6, col = id & 63;
    float v = red[(0 * 64 + row) * 66 + col] + red[(1 * 64 + row) * 66 + col] +
              red[(2 * 64 + row) * 66 + col] + red[(3 * 64 + row) * 66 + col];
    dst[row * 256 + col] = v;
  }
}

// ---------------- K3: reduce partials + mask + softmax + PV ----------------
// block: (b, 4 q-rows). 256 blocks.
__global__ __launch_bounds__(256) void k3_softpv(const float* __restrict__ part,
                                                 const float* __restrict__ lin,
                                                 const float* __restrict__ V,
                                                 const void* __restrict__ maskp,
                                                 const int* __restrict__ flagp,
                                                 float* __restrict__ out) {
  const int b = blockIdx.x >> 6;
  const int q0 = (blockIdx.x & 63) * 4;
  __shared__ float att[4 * 260];
  __shared__ float rowsum[4];
  __shared__ float red[8 * 4 * 264];
  const int t = threadIdx.x;
  const int flag = *flagp;
  const unsigned char* m8 = (const unsigned char*)maskp;
  const int* m32 = (const int*)maskp;
  // phase 1: assemble scores
#pragma unroll
  for (int s = 0; s < 4; ++s) {
    int id = t + s * 256;
    int row = id >> 8, col = id & 255;
    size_t base = ((size_t)b * 256 + q0 + row) * 256 + col;
    float v = part[base] + part[base + 262144] + part[base + 2 * 262144] +
              part[base + 3 * 262144];
    v += lin[b * 256 + q0 + row] + lin[1024 + b * 256 + col];
    bool masked = flag ? (m8[b * 256 + col] != 0) : (m32[b * 256 + col] != 0);
    att[row * 260 + col] = masked ? -1e9f : v;
  }
  __syncthreads();
  // phase 2: softmax (wave w -> row w), store unnormalized exp
  const int w = t >> 6, lane = t & 63;
  {
    float m = -1e30f;
#pragma unroll
    for (int u = 0; u < 4; ++u) m = fmaxf(m, att[w * 260 + lane + 64 * u]);
#pragma unroll
    for (int o = 32; o; o >>= 1) m = fmaxf(m, __shfl_xor(m, o, 64));
    float ssum = 0.f;
#pragma unroll
    for (int u = 0; u < 4; ++u) {
      float e = __expf(att[w * 260 + lane + 64 * u] - m);
      att[w * 260 + lane + 64 * u] = e;
      ssum += e;
    }
#pragma unroll
    for (int o = 32; o; o >>= 1) ssum += __shfl_xor(ssum, o, 64);
    if (lane == 0) rowsum[w] = ssum;
  }
  __syncthreads();
  // phase 3: PV, V streamed from global (L2-resident), k split across kg
  const int vg = t & 31, kg = t >> 5;
  const int v0 = vg * 8;
  const float* Vb = V + (size_t)b * 65536;
  float acc[4][8] = {};
#pragma unroll 1
  for (int kk = 0; kk < 32; ++kk) {
    int k = kk * 8 + kg;
    float4 va = *(const float4*)&Vb[k * 256 + v0];
    float4 vb = *(const float4*)&Vb[k * 256 + v0 + 4];
    float aw[4];
#pragma unroll
    for (int q = 0; q < 4; ++q) aw[q] = att[q * 260 + k];
#pragma unroll
    for (int q = 0; q < 4; ++q) {
      acc[q][0] = fmaf(aw[q], va.x, acc[q][0]);
      acc[q][1] = fmaf(aw[q], va.y, acc[q][1]);
      acc[q][2] = fmaf(aw[q], va.z, acc[q][2]);
      acc[q][3] = fmaf(aw[q], va.w, acc[q][3]);
      acc[q][4] = fmaf(aw[q], vb.x, acc[q][4]);
      acc[q][5] = fmaf(aw[q], vb.y, acc[q][5]);
      acc[q][6] = fmaf(aw[q], vb.z, acc[q][6]);
      acc[q][7] = fmaf(aw[q], vb.w, acc[q][7]);
    }
  }
#pragma unroll
  for (int q = 0; q < 4; ++q) {
    *(float4*)&red[(kg * 4 + q) * 264 + v0] =
        make_float4(acc[q][0], acc[q][1], acc[q][2], acc[q][3]);
    *(float4*)&red[(kg * 4 + q) * 264 + v0 + 4] =
        make_float4(acc[q][4], acc[q][5], acc[q][6], acc[q][7]);
  }
  __syncthreads();
#pragma unroll
  for (int s = 0; s < 4; ++s) {
    int id = t + s * 256;
    int row = id >> 8, col = id & 255;
    float v = 0.f;
#pragma unroll
    for (int g = 0; g < 8; ++g) v += red[(g * 4 + row) * 264 + col];
    out[((size_t)b * 256 + q0 + row) * 256 + col] = v / rowsum[row];
  }
}

extern "C" void kernel_launch(void* const* d_in, const int* in_sizes, int n_in,
                              void* d_out, int out_size, void* d_ws, size_t ws_size,
                              hipStream_t stream) {
  const float* Q = (const float*)d_in[0];
  const float* K = (const float*)d_in[1];
  const float* V = (const float*)d_in[2];
  const void* mask = d_in[3];
  const float* W1 = (const float*)d_in[4];
  const float* b1 = (const float*)d_in[5];
  const float* W2 = (const float*)d_in[6];
  float* ws = (float*)d_ws;
  float* hh = ws + HH_OFF;
  float* lin = ws + LIN_OFF;
  float* part = ws + PART_OFF;
  int* flagp = (int*)(ws + FLAG_OFF);
  float* out = (float*)d_out;

  k1_gemm<<<dim3(256), dim3(256), 0, stream>>>(Q, K, W1, b1, hh);
  k1b_lin<<<dim3(512), dim3(256), 0, stream>>>(hh, W2, mask, lin, flagp);
  k2_abs<<<dim3(256), dim3(256), 0, stream>>>(hh, W2, part);
  k3_softpv<<<dim3(256), dim3(256), 0, stream>>>(part, lin, V, mask, flagp, out);
}